// Round 5
// baseline (206.434 us; speedup 1.0000x reference)
//
#include <hip/hip_runtime.h>
#include <cstdint>
#include <cstddef>

#define B_N 4096
#define V_N 6
#define D_N 256
#define CHUNK 8
#define NCHUNK 80              // sum over rows i=0..31 of ceil((i+1)/8)
#define NGRAM (NCHUNK * V_N)   // 480 blocks total (>= all work), 2/CU resident

typedef int i32x4 __attribute__((ext_vector_type(4)));

// i8 encoding: q = round(zn * C), C = sqrt(2)*S -> dot_q = C^2 * sim,
// exp arg = acc * (2/C^2). C=298: element clamp at zn=127/298=0.426
// (max expected |zn| ~ 0.38 over 1.6e9 gaussians), acc max C^2 < 2^31.
#define QC 298.0f
#define INV_C2_X2 (2.0f / (QC * QC))

// Monotonic barrier/ticket counters in device globals: NOT in the poisoned
// workspace, never reset. Launch L's 480 tickets are exactly [480L, 480L+480);
// a block with ticket t spins until ctr >= (t/480+1)*480. Survives repeated
// timed launches and rocprof replays with zero per-launch init.
__device__ int g_bar = 0;   // phase1 -> phase2 grid barrier
__device__ int g_fin = 0;   // finalize election

// async global->LDS, 16B per lane. LDS dest is wave-uniform base + lane*16.
__device__ __forceinline__ void async_load16(void* lds, const void* gmem) {
  __builtin_amdgcn_global_load_lds(
      (const __attribute__((address_space(1))) unsigned int*)gmem,
      (__attribute__((address_space(3))) unsigned int*)lds,
      16, 0, 0);
}

// Single dispatch: phase1 norm+quantize+pos (grid-strided, wave-per-sample)
// -> software grid barrier -> phase2 persistent-chunk i8 gram -> last-block
// finalize. All blocks co-resident (launch_bounds(256,2): 512 slots >= 480).
__global__ __launch_bounds__(256, 2) void mega_kernel(
    const float* __restrict__ z, signed char* __restrict__ znb,
    float* __restrict__ pos_blk, float* __restrict__ neg_blk,
    float* __restrict__ out) {
  __shared__ signed char As[128][256];     // 32 KB, full-K A panel
  __shared__ signed char Bs[2][128][128];  // 2 x 16 KB, B half-panels
  __shared__ float red[4];
  __shared__ float pr[4], nr[4];
  __shared__ int lastblk;

  const int bx = blockIdx.x;    // 0..479
  const int tid = threadIdx.x;  // 256
  const int lane = tid & 63;
  const int w = tid >> 6;

  // ---------------- phase 1: normalize + quantize + pos ----------------
  float pacc = 0.0f;
  for (int b = bx * 4 + w; b < B_N; b += NGRAM * 4) {
    const float4* zb4 = (const float4*)(z + (size_t)b * (V_N * D_N));
    float4 x[V_N];
#pragma unroll
    for (int v = 0; v < V_N; ++v) x[v] = zb4[v * 64 + lane];

    float s[21];
    {
      int p = 0;
#pragma unroll
      for (int v = 0; v < V_N; ++v)
#pragma unroll
        for (int u = v; u < V_N; ++u) {
          s[p] = x[v].x * x[u].x + x[v].y * x[u].y +
                 x[v].z * x[u].z + x[v].w * x[u].w;
          ++p;
        }
    }
#pragma unroll
    for (int off = 1; off < 64; off <<= 1)
#pragma unroll
      for (int q = 0; q < 21; ++q)
        s[q] += __shfl_xor(s[q], off);

    const int selfidx[V_N] = {0, 6, 11, 15, 18, 20};
    float inv[V_N];
#pragma unroll
    for (int v = 0; v < V_N; ++v) inv[v] = rsqrtf(s[selfidx[v]]);

#pragma unroll
    for (int v = 0; v < V_N; ++v) {
      const float sc = inv[v] * QC;
      int q0 = (int)rintf(fminf(127.0f, fmaxf(-127.0f, x[v].x * sc)));
      int q1 = (int)rintf(fminf(127.0f, fmaxf(-127.0f, x[v].y * sc)));
      int q2 = (int)rintf(fminf(127.0f, fmaxf(-127.0f, x[v].z * sc)));
      int q3 = (int)rintf(fminf(127.0f, fmaxf(-127.0f, x[v].w * sc)));
      int packed = (q0 & 255) | ((q1 & 255) << 8) | ((q2 & 255) << 16)
                 | ((q3 & 255) << 24);
      ((int*)(znb + ((size_t)v * B_N + b) * D_N))[lane] = packed;
    }

    {
      int p = 0;
#pragma unroll
      for (int v = 0; v < V_N; ++v)
#pragma unroll
        for (int u = v; u < V_N; ++u) {
          if (u > v) pacc += __expf(2.0f * (1.0f - s[p] * inv[v] * inv[u]));
          ++p;
        }
    }
  }
  if (lane == 0) red[w] = pacc;
  __syncthreads();
  if (tid == 0) pos_blk[bx] = red[0] + red[1] + red[2] + red[3];

  // ---------------- grid barrier (monotonic ticket) ----------------
  if (tid == 0) {
    __threadfence();  // release: znb + pos_blk visible device-wide
    int ticket = __hip_atomic_fetch_add(&g_bar, 1, __ATOMIC_ACQ_REL,
                                        __HIP_MEMORY_SCOPE_AGENT);
    const int target = (ticket / NGRAM + 1) * NGRAM;
    while (__hip_atomic_load(&g_bar, __ATOMIC_ACQUIRE,
                             __HIP_MEMORY_SCOPE_AGENT) < target)
      __builtin_amdgcn_s_sleep(1);
  }
  __syncthreads();
  __threadfence();  // acquire side for all waves (L1/L2 coherence per G16)

  // ---------------- phase 2: persistent-chunk i8 gram ----------------
  const int v = bx / NCHUNK;
  const int cid = bx % NCHUNK;

  // map cid -> (row i, chunk rem), big rows first (LPT)
  int i = 31, rem = cid;
  for (int r = 31; r >= 0; --r) {
    const int nc = (r + 8) >> 3;           // ceil((r+1)/8)
    if (rem < nc) { i = r; break; }
    rem -= nc;
  }
  const int j0 = rem * CHUNK;
  const int jend = min(j0 + CHUNK, i + 1);
  const int nsteps = 2 * (jend - j0);

  const signed char* Zv = znb + (size_t)v * B_N * D_N;
  const signed char* Ag = Zv + (size_t)(i * 128) * D_N;

  const int wr = w >> 1;   // wave row 0..1 (64-row strip of C)
  const int wc = w & 1;    // wave col 0..1 (64-col strip of C)
  const int kc = lane >> 4;               // operand 16B-chunk index (0..3)
  const int mrow = wr * 64 + (lane & 15); // A fragment base row
  const int ncol = wc * 64 + (lane & 15); // B fragment base row (= C column)

  signed char* AsF = &As[0][0];

  // prologue: issue A (8 load-instrs) + B steps 0,1 (4 each)
#pragma unroll
  for (int q = 0; q < 8; ++q) {
    const int sA = tid + 256 * q;          // 0..2047
    const int row = sA >> 4;               // 0..127
    const int gc = (sA & 15) ^ (row & 15); // 256B-row swizzle on global src
    async_load16(AsF + sA * 16, Ag + (size_t)row * D_N + gc * 16);
  }
#pragma unroll
  for (int st = 0; st < 2; ++st) {
    if (st < nsteps) {
      const int jn = j0 + (st >> 1), hn = st & 1;
      const signed char* Bg = Zv + (size_t)(jn * 128) * D_N + hn * 128;
      signed char* BsF = &Bs[st & 1][0][0];
#pragma unroll
      for (int q = 0; q < 4; ++q) {
        const int s = tid + 256 * q;       // 0..1023
        const int row = s >> 3;            // 0..127
        const int gc = (s & 7) ^ (row & 7);
        async_load16(BsF + s * 16, Bg + (size_t)row * D_N + gc * 16);
      }
    }
  }
  asm volatile("s_waitcnt vmcnt(4)" ::: "memory");
  __builtin_amdgcn_sched_barrier(0);
  __builtin_amdgcn_s_barrier();

  float wsum = 0.0f;
  int s = 0;
  for (int jt = j0; jt < jend; ++jt) {
    i32x4 c[4][4];
#pragma unroll
    for (int a = 0; a < 4; ++a)
#pragma unroll
      for (int b2 = 0; b2 < 4; ++b2) c[a][b2] = (i32x4){0, 0, 0, 0};

#pragma unroll
    for (int h = 0; h < 2; ++h, ++s) {
      const signed char* BsF = &Bs[s & 1][0][0];
      __builtin_amdgcn_s_setprio(1);
#pragma unroll
      for (int kk = 0; kk < 2; ++kk) {
        const int cb8 = kk * 4 + kc;           // B chunk 0..7 (128B rows)
        const int ca16 = h * 8 + kk * 4 + kc;  // A chunk 0..15 (256B rows)
        i32x4 af[4], bfr[4];
#pragma unroll
        for (int f = 0; f < 4; ++f) {
          const int ra = mrow + 16 * f;
          const int rb = ncol + 16 * f;
          af[f]  = *(const i32x4*)(AsF + ra * 256 + ((ca16 ^ (ra & 15)) * 16));
          bfr[f] = *(const i32x4*)(BsF + rb * 128 + ((cb8 ^ (rb & 7)) * 16));
        }
#pragma unroll
        for (int fm = 0; fm < 4; ++fm)
#pragma unroll
          for (int fn = 0; fn < 4; ++fn)
            c[fm][fn] = __builtin_amdgcn_mfma_i32_16x16x64_i8(
                af[fm], bfr[fn], c[fm][fn], 0, 0, 0);
      }
      __builtin_amdgcn_s_setprio(0);
      __builtin_amdgcn_s_barrier();  // Bs[s&1] reads done before overwrite
      const int sn = s + 2;
      if (sn < nsteps) {
        const int jn = j0 + (sn >> 1), hn = sn & 1;
        const signed char* Bg = Zv + (size_t)(jn * 128) * D_N + hn * 128;
        signed char* BsN = &Bs[s & 1][0][0];
#pragma unroll
        for (int q = 0; q < 4; ++q) {
          const int sg = tid + 256 * q;
          const int row = sg >> 3;
          const int gc = (sg & 7) ^ (row & 7);
          async_load16(BsN + sg * 16, Bg + (size_t)row * D_N + gc * 16);
        }
      }
      // tile epilogue (pure VALU) overlaps S(s+1) flight; diag test hoisted
      if (h == 1) {
        float tsum = 0.0f;
        if (i != jt) {
#pragma unroll
          for (int fm = 0; fm < 4; ++fm)
#pragma unroll
            for (int fn = 0; fn < 4; ++fn)
#pragma unroll
              for (int r = 0; r < 4; ++r)
                tsum += __expf((float)c[fm][fn][r] * INV_C2_X2);
          wsum += 2.0f * tsum;             // symmetric twin tile
        } else {
          const int rb0 = wr * 64 + (lane >> 4) * 4;
          const int cb0 = wc * 64 + (lane & 15);
#pragma unroll
          for (int fm = 0; fm < 4; ++fm)
#pragma unroll
            for (int fn = 0; fn < 4; ++fn) {
              const int gcol = cb0 + fn * 16;
#pragma unroll
              for (int r = 0; r < 4; ++r) {
                const int grow = rb0 + fm * 16 + r;
                float e = __expf((float)c[fm][fn][r] * INV_C2_X2);
                tsum += (grow == gcol) ? 0.0f : e;
              }
            }
          wsum += tsum;
        }
      }
      if (sn < nsteps) {
        asm volatile("s_waitcnt vmcnt(4)" ::: "memory");
      } else {
        asm volatile("s_waitcnt vmcnt(0)" ::: "memory");
      }
      __builtin_amdgcn_sched_barrier(0);
      __builtin_amdgcn_s_barrier();
    }
  }

  // per-block reduction + last-block finalize (monotonic election)
#pragma unroll
  for (int off = 32; off > 0; off >>= 1) wsum += __shfl_down(wsum, off);
  if (lane == 0) red[w] = wsum;
  __syncthreads();
  if (tid == 0) {
    neg_blk[bx] = red[0] + red[1] + red[2] + red[3];
    __threadfence();                       // publish neg_blk device-wide
    int t2 = __hip_atomic_fetch_add(&g_fin, 1, __ATOMIC_ACQ_REL,
                                    __HIP_MEMORY_SCOPE_AGENT);
    lastblk = ((t2 % NGRAM) == NGRAM - 1) ? 1 : 0;
  }
  __syncthreads();

  if (lastblk) {
    // both partial arrays were written this-kernel, possibly on other XCDs:
    // agent-scope atomic loads bypass stale per-XCD caches.
    float p = 0.0f, n = 0.0f;
    for (int idx = tid; idx < NGRAM; idx += 256) {
      p += __hip_atomic_load(&pos_blk[idx], __ATOMIC_RELAXED,
                             __HIP_MEMORY_SCOPE_AGENT);
      n += __hip_atomic_load(&neg_blk[idx], __ATOMIC_RELAXED,
                             __HIP_MEMORY_SCOPE_AGENT);
    }
#pragma unroll
    for (int off = 32; off > 0; off >>= 1) {
      p += __shfl_down(p, off);
      n += __shfl_down(n, off);
    }
    if (lane == 0) { pr[w] = p; nr[w] = n; }
    __syncthreads();
    if (tid == 0) {
      float P = pr[0] + pr[1] + pr[2] + pr[3];
      float N = nr[0] + nr[1] + nr[2] + nr[3];
      // sum(pos) = (6*B + 2P)/36 = B/6 + P/18 ; sum(neg) = N/(B-1)
      out[0] = (1.0f / 32.0f) * ((float)B_N / 6.0f + P / 18.0f) +
               0.0039f * (N / (float)(B_N - 1));
    }
  }
}

extern "C" void kernel_launch(void* const* d_in, const int* in_sizes, int n_in,
                              void* d_out, int out_size, void* d_ws, size_t ws_size,
                              hipStream_t stream) {
  const float* z = (const float*)d_in[0];
  float* out = (float*)d_out;
  // ws: [0, 2KB) pos partials (480 f32) | 8KB: neg partials (480 f32) |
  //     32KB: i8 Zn [V][B][D] (6.3 MB). All fully overwritten every launch.
  //     Barrier counters are __device__ globals (monotonic, no init needed).
  float* pos_blk = (float*)d_ws;
  float* neg_blk = (float*)((char*)d_ws + 8192);
  signed char* znb = (signed char*)((char*)d_ws + 32768);

  mega_kernel<<<NGRAM, 256, 0, stream>>>(z, znb, pos_blk, neg_blk, out);
}

// Round 6
// 100.367 us; speedup vs baseline: 2.0568x; 2.0568x over previous
//
#include <hip/hip_runtime.h>
#include <cstdint>
#include <cstddef>

#define B_N 4096
#define V_N 6
#define D_N 256
#define CHUNK 8
#define NCHUNK 80              // sum over rows i=0..31 of ceil((i+1)/8)
#define NGRAM (NCHUNK * V_N)   // 480 gram blocks
#define NPOSB 1024             // norm_pos blocks (block partials)

typedef int i32x4 __attribute__((ext_vector_type(4)));

// i8 encoding: q = round(zn * C), C = sqrt(2)*S -> dot_q = C^2 * sim,
// exp arg = acc * (2/C^2). C=298: element clamp at zn=127/298=0.426
// (max expected |zn| ~ 0.38 over 1.6e9 gaussians), acc max C^2 < 2^31.
#define QC 298.0f
#define INV_C2_X2 (2.0f / (QC * QC))

// Monotonic election counter in a device global: never reset; each gram
// launch adds exactly NGRAM tickets, so (t % NGRAM)==NGRAM-1 elects exactly
// one block per launch. Survives timed loops and rocprof replays.
// NO __threadfence anywhere: R4/R5 showed device-scope fences compile to
// cache-wide wbl2/inv walks (~storm at 480-1920 fences). Ordering instead:
// agent-scope relaxed (sc1) stores -> s_waitcnt vmcnt(0) -> relaxed ticket.
__device__ int g_fin = 0;

// async global->LDS, 16B per lane. LDS dest is wave-uniform base + lane*16.
__device__ __forceinline__ void async_load16(void* lds, const void* gmem) {
  __builtin_amdgcn_global_load_lds(
      (const __attribute__((address_space(1))) unsigned int*)gmem,
      (__attribute__((address_space(3))) unsigned int*)lds,
      16, 0, 0);
}

// Kernel A: wave-per-sample, register-resident, zero LDS in the hot path.
// 21 simultaneous 6-step shfl_xor butterflies; per-block pos partial.
// znb/pos_blk coherence to the next kernel is free (dispatch boundary).
__global__ __launch_bounds__(256) void norm_pos_kernel(
    const float* __restrict__ z, signed char* __restrict__ znb,
    float* __restrict__ pos_blk) {
  const int lane = threadIdx.x & 63;
  const int w = threadIdx.x >> 6;          // wave 0..3
  const int b = blockIdx.x * 4 + w;        // sample
  __shared__ float red[4];

  const float4* zb4 = (const float4*)(z + (size_t)b * (V_N * D_N));
  float4 x[V_N];
#pragma unroll
  for (int v = 0; v < V_N; ++v) x[v] = zb4[v * 64 + lane];

  float s[21];
  {
    int p = 0;
#pragma unroll
    for (int v = 0; v < V_N; ++v)
#pragma unroll
      for (int u = v; u < V_N; ++u) {
        s[p] = x[v].x * x[u].x + x[v].y * x[u].y +
               x[v].z * x[u].z + x[v].w * x[u].w;
        ++p;
      }
  }
#pragma unroll
  for (int off = 1; off < 64; off <<= 1)
#pragma unroll
    for (int q = 0; q < 21; ++q)
      s[q] += __shfl_xor(s[q], off);

  const int selfidx[V_N] = {0, 6, 11, 15, 18, 20};
  float inv[V_N];
#pragma unroll
  for (int v = 0; v < V_N; ++v) inv[v] = rsqrtf(s[selfidx[v]]);

#pragma unroll
  for (int v = 0; v < V_N; ++v) {
    const float sc = inv[v] * QC;
    int q0 = (int)rintf(fminf(127.0f, fmaxf(-127.0f, x[v].x * sc)));
    int q1 = (int)rintf(fminf(127.0f, fmaxf(-127.0f, x[v].y * sc)));
    int q2 = (int)rintf(fminf(127.0f, fmaxf(-127.0f, x[v].z * sc)));
    int q3 = (int)rintf(fminf(127.0f, fmaxf(-127.0f, x[v].w * sc)));
    int packed = (q0 & 255) | ((q1 & 255) << 8) | ((q2 & 255) << 16)
               | ((q3 & 255) << 24);
    ((int*)(znb + ((size_t)v * B_N + b) * D_N))[lane] = packed;
  }

  float psum = 0.0f;
  {
    int p = 0;
#pragma unroll
    for (int v = 0; v < V_N; ++v)
#pragma unroll
      for (int u = v; u < V_N; ++u) {
        if (u > v) psum += __expf(2.0f * (1.0f - s[p] * inv[v] * inv[u]));
        ++p;
      }
  }
  if (lane == 0) red[w] = psum;
  __syncthreads();
  if (threadIdx.x == 0)
    pos_blk[blockIdx.x] = red[0] + red[1] + red[2] + red[3];
}

// Kernel B: persistent-chunk i8 gram (R2-verbatim internals, verified 2x)
// + FENCE-FREE last-block finalize: sc1 store of the partial, vmcnt(0) to
// complete it at the coherent point, relaxed monotonic ticket, elected block
// reduces via agent-scope loads (R4-proven read path) and writes out.
__global__ __launch_bounds__(256, 2) void gram_kernel(
    const signed char* __restrict__ znb, const float* __restrict__ pos_blk,
    float* __restrict__ neg_blk, float* __restrict__ out) {
  const int v = blockIdx.y;
  const int bid = blockIdx.y * NCHUNK + blockIdx.x;

  // map blockIdx.x -> (row i, chunk rem), big rows first (LPT dispatch)
  int i = 31, rem = blockIdx.x;
  for (int r = 31; r >= 0; --r) {
    const int nc = (r + 8) >> 3;           // ceil((r+1)/8)
    if (rem < nc) { i = r; break; }
    rem -= nc;
  }
  const int j0 = rem * CHUNK;
  const int jend = min(j0 + CHUNK, i + 1);
  const int nsteps = 2 * (jend - j0);

  const signed char* Zv = znb + (size_t)v * B_N * D_N;
  const signed char* Ag = Zv + (size_t)(i * 128) * D_N;

  __shared__ signed char As[128][256];     // 32 KB, full-K A panel
  __shared__ signed char Bs[2][128][128];  // 2 x 16 KB, B half-panels
  __shared__ float red[4];
  __shared__ float pr[4], nr[4];
  __shared__ int lastblk;

  const int tid = threadIdx.x;  // 256
  const int lane = tid & 63;
  const int w = tid >> 6;
  const int wr = w >> 1;   // wave row 0..1 (64-row strip of C)
  const int wc = w & 1;    // wave col 0..1 (64-col strip of C)
  const int kc = lane >> 4;               // operand 16B-chunk index (0..3)
  const int mrow = wr * 64 + (lane & 15); // A fragment base row
  const int ncol = wc * 64 + (lane & 15); // B fragment base row (= C column)

  signed char* AsF = &As[0][0];

  // prologue: issue A (8 load-instrs) + B steps 0,1 (4 each)
#pragma unroll
  for (int q = 0; q < 8; ++q) {
    const int sA = tid + 256 * q;          // 0..2047
    const int row = sA >> 4;               // 0..127
    const int gc = (sA & 15) ^ (row & 15); // 256B-row swizzle on global src
    async_load16(AsF + sA * 16, Ag + (size_t)row * D_N + gc * 16);
  }
#pragma unroll
  for (int st = 0; st < 2; ++st) {
    if (st < nsteps) {
      const int jn = j0 + (st >> 1), hn = st & 1;
      const signed char* Bg = Zv + (size_t)(jn * 128) * D_N + hn * 128;
      signed char* BsF = &Bs[st & 1][0][0];
#pragma unroll
      for (int q = 0; q < 4; ++q) {
        const int s = tid + 256 * q;       // 0..1023
        const int row = s >> 3;            // 0..127
        const int gc = (s & 7) ^ (row & 7);
        async_load16(BsF + s * 16, Bg + (size_t)row * D_N + gc * 16);
      }
    }
  }
  // A(8) + S0(4) landed; S1(4) may still be in flight
  asm volatile("s_waitcnt vmcnt(4)" ::: "memory");
  __builtin_amdgcn_sched_barrier(0);
  __builtin_amdgcn_s_barrier();

  float wsum = 0.0f;
  int s = 0;
  for (int jt = j0; jt < jend; ++jt) {
    i32x4 c[4][4];
#pragma unroll
    for (int a = 0; a < 4; ++a)
#pragma unroll
      for (int b2 = 0; b2 < 4; ++b2) c[a][b2] = (i32x4){0, 0, 0, 0};

#pragma unroll
    for (int h = 0; h < 2; ++h, ++s) {
      const signed char* BsF = &Bs[s & 1][0][0];
      __builtin_amdgcn_s_setprio(1);
#pragma unroll
      for (int kk = 0; kk < 2; ++kk) {
        const int cb8 = kk * 4 + kc;           // B chunk 0..7 (128B rows)
        const int ca16 = h * 8 + kk * 4 + kc;  // A chunk 0..15 (256B rows)
        i32x4 af[4], bfr[4];
#pragma unroll
        for (int f = 0; f < 4; ++f) {
          const int ra = mrow + 16 * f;
          const int rb = ncol + 16 * f;
          af[f]  = *(const i32x4*)(AsF + ra * 256 + ((ca16 ^ (ra & 15)) * 16));
          bfr[f] = *(const i32x4*)(BsF + rb * 128 + ((cb8 ^ (rb & 7)) * 16));
        }
#pragma unroll
        for (int fm = 0; fm < 4; ++fm)
#pragma unroll
          for (int fn = 0; fn < 4; ++fn)
            c[fm][fn] = __builtin_amdgcn_mfma_i32_16x16x64_i8(
                af[fm], bfr[fn], c[fm][fn], 0, 0, 0);
      }
      __builtin_amdgcn_s_setprio(0);
      __builtin_amdgcn_s_barrier();  // Bs[s&1] reads done before overwrite
      const int sn = s + 2;
      if (sn < nsteps) {
        const int jn = j0 + (sn >> 1), hn = sn & 1;
        const signed char* Bg = Zv + (size_t)(jn * 128) * D_N + hn * 128;
        signed char* BsN = &Bs[s & 1][0][0];
#pragma unroll
        for (int q = 0; q < 4; ++q) {
          const int sg = tid + 256 * q;
          const int row = sg >> 3;
          const int gc = (sg & 7) ^ (row & 7);
          async_load16(BsN + sg * 16, Bg + (size_t)row * D_N + gc * 16);
        }
      }
      // tile epilogue (pure VALU) overlaps S(s+1) flight; diag test hoisted
      if (h == 1) {
        float tsum = 0.0f;
        if (i != jt) {
#pragma unroll
          for (int fm = 0; fm < 4; ++fm)
#pragma unroll
            for (int fn = 0; fn < 4; ++fn)
#pragma unroll
              for (int r = 0; r < 4; ++r)
                tsum += __expf((float)c[fm][fn][r] * INV_C2_X2);
          wsum += 2.0f * tsum;             // symmetric twin tile
        } else {
          const int rb0 = wr * 64 + (lane >> 4) * 4;
          const int cb0 = wc * 64 + (lane & 15);
#pragma unroll
          for (int fm = 0; fm < 4; ++fm)
#pragma unroll
            for (int fn = 0; fn < 4; ++fn) {
              const int gcol = cb0 + fn * 16;
#pragma unroll
              for (int r = 0; r < 4; ++r) {
                const int grow = rb0 + fm * 16 + r;
                float e = __expf((float)c[fm][fn][r] * INV_C2_X2);
                tsum += (grow == gcol) ? 0.0f : e;
              }
            }
          wsum += tsum;
        }
      }
      if (sn < nsteps) {
        asm volatile("s_waitcnt vmcnt(4)" ::: "memory");
      } else {
        asm volatile("s_waitcnt vmcnt(0)" ::: "memory");
      }
      __builtin_amdgcn_sched_barrier(0);
      __builtin_amdgcn_s_barrier();
    }
  }

  // per-block reduction, fence-free publish + monotonic election
#pragma unroll
  for (int off = 32; off > 0; off >>= 1) wsum += __shfl_down(wsum, off);
  if (lane == 0) red[w] = wsum;
  __syncthreads();
  if (tid == 0) {
    // sc1 relaxed store -> visible at the device coherent point...
    __hip_atomic_store(&neg_blk[bid], red[0] + red[1] + red[2] + red[3],
                       __ATOMIC_RELAXED, __HIP_MEMORY_SCOPE_AGENT);
    // ...and COMPLETE before the ticket increments (no wbl2/inv needed)
    asm volatile("s_waitcnt vmcnt(0)" ::: "memory");
    int t2 = __hip_atomic_fetch_add(&g_fin, 1, __ATOMIC_RELAXED,
                                    __HIP_MEMORY_SCOPE_AGENT);
    lastblk = ((t2 % NGRAM) == NGRAM - 1) ? 1 : 0;
  }
  __syncthreads();

  if (lastblk) {
    // pos_blk: written by the previous dispatch -> coherent via plain loads.
    // neg_blk: written this-dispatch on other XCDs -> agent-scope loads
    // (bypass stale per-XCD L2; R4-verified, absmax 0.0).
    float p = 0.0f, n = 0.0f;
    for (int idx = tid; idx < NPOSB; idx += 256) p += pos_blk[idx];
    for (int idx = tid; idx < NGRAM; idx += 256)
      n += __hip_atomic_load(&neg_blk[idx], __ATOMIC_RELAXED,
                             __HIP_MEMORY_SCOPE_AGENT);
#pragma unroll
    for (int off = 32; off > 0; off >>= 1) {
      p += __shfl_down(p, off);
      n += __shfl_down(n, off);
    }
    if (lane == 0) { pr[w] = p; nr[w] = n; }
    __syncthreads();
    if (tid == 0) {
      float P = pr[0] + pr[1] + pr[2] + pr[3];
      float N = nr[0] + nr[1] + nr[2] + nr[3];
      // sum(pos) = (6*B + 2P)/36 = B/6 + P/18 ; sum(neg) = N/(B-1)
      out[0] = (1.0f / 32.0f) * ((float)B_N / 6.0f + P / 18.0f) +
               0.0039f * (N / (float)(B_N - 1));
    }
  }
}

extern "C" void kernel_launch(void* const* d_in, const int* in_sizes, int n_in,
                              void* d_out, int out_size, void* d_ws, size_t ws_size,
                              hipStream_t stream) {
  const float* z = (const float*)d_in[0];
  float* out = (float*)d_out;
  // ws: [0, 4KB) pos partials (1024 f32) | 8KB: neg partials (480 f32) |
  //     32KB: i8 Zn [V][B][D] (6.3 MB). All fully overwritten every launch.
  //     Election counter is a __device__ global (monotonic, no init).
  float* pos_blk = (float*)d_ws;
  float* neg_blk = (float*)((char*)d_ws + 8192);
  signed char* znb = (signed char*)((char*)d_ws + 32768);

  norm_pos_kernel<<<NPOSB, 256, 0, stream>>>(z, znb, pos_blk);
  dim3 grid(NCHUNK, V_N, 1);
  gram_kernel<<<grid, 256, 0, stream>>>(znb, pos_blk, neg_blk, out);
}

// Round 7
// 98.870 us; speedup vs baseline: 2.0879x; 1.0151x over previous
//
#include <hip/hip_runtime.h>
#include <cstdint>
#include <cstddef>

#define B_N 4096
#define V_N 6
#define D_N 256
#define CHUNK 8
#define NCHUNK 80              // sum over rows i=0..31 of ceil((i+1)/8)
#define NGRAM (NCHUNK * V_N)   // 480 gram blocks
#define NPOSB 1024             // norm_pos blocks (block partials)

typedef int i32x4 __attribute__((ext_vector_type(4)));

// i8 encoding: q = round(zn * C), C = sqrt(2)*S -> dot_q = C^2 * sim,
// exp arg = acc * (2/C^2). C=298: element clamp at zn=127/298=0.426
// (max expected |zn| ~ 0.38 over 1.6e9 gaussians), acc max C^2 < 2^31.
#define QC 298.0f
#define INV_C2_X2 (2.0f / (QC * QC))

// Monotonic election counter (device global, never reset): each gram launch
// adds exactly NGRAM tickets -> (t % NGRAM)==NGRAM-1 elects one block per
// launch; survives timed loops and rocprof replays. NO __threadfence
// anywhere (R5: device fences = cache-wide wbl2/inv storm). Ordering:
// agent-scope relaxed store -> s_waitcnt vmcnt(0) -> relaxed ticket.
__device__ int g_fin = 0;

// async global->LDS, 16B per lane. LDS dest is wave-uniform base + lane*16.
__device__ __forceinline__ void async_load16(void* lds, const void* gmem) {
  __builtin_amdgcn_global_load_lds(
      (const __attribute__((address_space(1))) unsigned int*)gmem,
      (__attribute__((address_space(3))) unsigned int*)lds,
      16, 0, 0);
}

// Kernel A (R6-verbatim): wave-per-sample, register-resident.
// 21 simultaneous 6-step shfl_xor butterflies; per-block pos partial.
__global__ __launch_bounds__(256) void norm_pos_kernel(
    const float* __restrict__ z, signed char* __restrict__ znb,
    float* __restrict__ pos_blk) {
  const int lane = threadIdx.x & 63;
  const int w = threadIdx.x >> 6;          // wave 0..3
  const int b = blockIdx.x * 4 + w;        // sample
  __shared__ float red[4];

  const float4* zb4 = (const float4*)(z + (size_t)b * (V_N * D_N));
  float4 x[V_N];
#pragma unroll
  for (int v = 0; v < V_N; ++v) x[v] = zb4[v * 64 + lane];

  float s[21];
  {
    int p = 0;
#pragma unroll
    for (int v = 0; v < V_N; ++v)
#pragma unroll
      for (int u = v; u < V_N; ++u) {
        s[p] = x[v].x * x[u].x + x[v].y * x[u].y +
               x[v].z * x[u].z + x[v].w * x[u].w;
        ++p;
      }
  }
#pragma unroll
  for (int off = 1; off < 64; off <<= 1)
#pragma unroll
    for (int q = 0; q < 21; ++q)
      s[q] += __shfl_xor(s[q], off);

  const int selfidx[V_N] = {0, 6, 11, 15, 18, 20};
  float inv[V_N];
#pragma unroll
  for (int v = 0; v < V_N; ++v) inv[v] = rsqrtf(s[selfidx[v]]);

#pragma unroll
  for (int v = 0; v < V_N; ++v) {
    const float sc = inv[v] * QC;
    int q0 = (int)rintf(fminf(127.0f, fmaxf(-127.0f, x[v].x * sc)));
    int q1 = (int)rintf(fminf(127.0f, fmaxf(-127.0f, x[v].y * sc)));
    int q2 = (int)rintf(fminf(127.0f, fmaxf(-127.0f, x[v].z * sc)));
    int q3 = (int)rintf(fminf(127.0f, fmaxf(-127.0f, x[v].w * sc)));
    int packed = (q0 & 255) | ((q1 & 255) << 8) | ((q2 & 255) << 16)
               | ((q3 & 255) << 24);
    ((int*)(znb + ((size_t)v * B_N + b) * D_N))[lane] = packed;
  }

  float psum = 0.0f;
  {
    int p = 0;
#pragma unroll
    for (int v = 0; v < V_N; ++v)
#pragma unroll
      for (int u = v; u < V_N; ++u) {
        if (u > v) psum += __expf(2.0f * (1.0f - s[p] * inv[v] * inv[u]));
        ++p;
      }
  }
  if (lane == 0) red[w] = psum;
  __syncthreads();
  if (threadIdx.x == 0)
    pos_blk[blockIdx.x] = red[0] + red[1] + red[2] + red[3];
}

// Kernel B: persistent-chunk i8 gram, now 512 threads / 8 waves per block
// over the same 128x128 tile (wave grid 2x4, per-wave 64x32 sub-tile).
// LDS unchanged (65.6 KB -> 2 blocks/CU) => waves/SIMD 2 -> 4: doubles
// latency-hiding for the per-step barrier+load-return holes, and halves
// per-wave serial epilogue. Fence-free last-block finalize (R6-verified).
__global__ __launch_bounds__(512, 4) void gram_kernel(
    const signed char* __restrict__ znb, const float* __restrict__ pos_blk,
    float* __restrict__ neg_blk, float* __restrict__ out) {
  const int v = blockIdx.y;
  const int bid = blockIdx.y * NCHUNK + blockIdx.x;

  // map blockIdx.x -> (row i, chunk rem), big rows first (LPT dispatch)
  int i = 31, rem = blockIdx.x;
  for (int r = 31; r >= 0; --r) {
    const int nc = (r + 8) >> 3;           // ceil((r+1)/8)
    if (rem < nc) { i = r; break; }
    rem -= nc;
  }
  const int j0 = rem * CHUNK;
  const int jend = min(j0 + CHUNK, i + 1);
  const int nsteps = 2 * (jend - j0);

  const signed char* Zv = znb + (size_t)v * B_N * D_N;
  const signed char* Ag = Zv + (size_t)(i * 128) * D_N;

  __shared__ signed char As[128][256];     // 32 KB, full-K A panel
  __shared__ signed char Bs[2][128][128];  // 2 x 16 KB, B half-panels
  __shared__ float red[8];
  __shared__ float pr[8], nr[8];
  __shared__ int lastblk;

  const int tid = threadIdx.x;  // 512
  const int lane = tid & 63;
  const int w = tid >> 6;       // wave 0..7
  const int wr = w >> 2;        // wave row 0..1 (64-row strip of C)
  const int wc = w & 3;         // wave col 0..3 (32-col strip of C)
  const int kc = lane >> 4;                // operand 16B-chunk index (0..3)
  const int mrow = wr * 64 + (lane & 15);  // A fragment base row
  const int ncol = wc * 32 + (lane & 15);  // B fragment base row (= C col)

  signed char* AsF = &As[0][0];

  // prologue: issue A (4 load-instrs/thread) + B steps 0,1 (2 each)
#pragma unroll
  for (int q = 0; q < 4; ++q) {
    const int sA = tid + 512 * q;          // 0..2047
    const int row = sA >> 4;               // 0..127
    const int gc = (sA & 15) ^ (row & 15); // 256B-row swizzle on global src
    async_load16(AsF + sA * 16, Ag + (size_t)row * D_N + gc * 16);
  }
#pragma unroll
  for (int st = 0; st < 2; ++st) {
    if (st < nsteps) {
      const int jn = j0 + (st >> 1), hn = st & 1;
      const signed char* Bg = Zv + (size_t)(jn * 128) * D_N + hn * 128;
      signed char* BsF = &Bs[st & 1][0][0];
#pragma unroll
      for (int q = 0; q < 2; ++q) {
        const int s = tid + 512 * q;       // 0..1023
        const int row = s >> 3;            // 0..127
        const int gc = (s & 7) ^ (row & 7);
        async_load16(BsF + s * 16, Bg + (size_t)row * D_N + gc * 16);
      }
    }
  }
  // A(4) + S0(2) landed; S1(2) may still be in flight
  asm volatile("s_waitcnt vmcnt(2)" ::: "memory");
  __builtin_amdgcn_sched_barrier(0);
  __builtin_amdgcn_s_barrier();

  float wsum = 0.0f;
  int s = 0;
  for (int jt = j0; jt < jend; ++jt) {
    i32x4 c[4][2];
#pragma unroll
    for (int a = 0; a < 4; ++a)
#pragma unroll
      for (int b2 = 0; b2 < 2; ++b2) c[a][b2] = (i32x4){0, 0, 0, 0};

#pragma unroll
    for (int h = 0; h < 2; ++h, ++s) {
      const signed char* BsF = &Bs[s & 1][0][0];
      __builtin_amdgcn_s_setprio(1);
#pragma unroll
      for (int kk = 0; kk < 2; ++kk) {
        const int cb8 = kk * 4 + kc;           // B chunk 0..7 (128B rows)
        const int ca16 = h * 8 + kk * 4 + kc;  // A chunk 0..15 (256B rows)
        i32x4 af[4], bfr[2];
#pragma unroll
        for (int f = 0; f < 4; ++f) {
          const int ra = mrow + 16 * f;
          af[f] = *(const i32x4*)(AsF + ra * 256 + ((ca16 ^ (ra & 15)) * 16));
        }
#pragma unroll
        for (int f = 0; f < 2; ++f) {
          const int rb = ncol + 16 * f;
          bfr[f] = *(const i32x4*)(BsF + rb * 128 + ((cb8 ^ (rb & 7)) * 16));
        }
#pragma unroll
        for (int fm = 0; fm < 4; ++fm)
#pragma unroll
          for (int fn = 0; fn < 2; ++fn)
            c[fm][fn] = __builtin_amdgcn_mfma_i32_16x16x64_i8(
                af[fm], bfr[fn], c[fm][fn], 0, 0, 0);
      }
      __builtin_amdgcn_s_setprio(0);
      __builtin_amdgcn_s_barrier();  // Bs[s&1] reads done before overwrite
      const int sn = s + 2;
      if (sn < nsteps) {
        const int jn = j0 + (sn >> 1), hn = sn & 1;
        const signed char* Bg = Zv + (size_t)(jn * 128) * D_N + hn * 128;
        signed char* BsN = &Bs[s & 1][0][0];
#pragma unroll
        for (int q = 0; q < 2; ++q) {
          const int sg = tid + 512 * q;
          const int row = sg >> 3;
          const int gc = (sg & 7) ^ (row & 7);
          async_load16(BsN + sg * 16, Bg + (size_t)row * D_N + gc * 16);
        }
      }
      // tile epilogue (pure VALU) overlaps S(s+1) flight; diag test hoisted
      if (h == 1) {
        float tsum = 0.0f;
        if (i != jt) {
#pragma unroll
          for (int fm = 0; fm < 4; ++fm)
#pragma unroll
            for (int fn = 0; fn < 2; ++fn)
#pragma unroll
              for (int r = 0; r < 4; ++r)
                tsum += __expf((float)c[fm][fn][r] * INV_C2_X2);
          wsum += 2.0f * tsum;             // symmetric twin tile
        } else {
          const int rb0 = wr * 64 + (lane >> 4) * 4;  // local row in tile
          const int cb0 = wc * 32 + (lane & 15);      // local col in tile
#pragma unroll
          for (int fm = 0; fm < 4; ++fm)
#pragma unroll
            for (int fn = 0; fn < 2; ++fn) {
              const int gcol = cb0 + fn * 16;
#pragma unroll
              for (int r = 0; r < 4; ++r) {
                const int grow = rb0 + fm * 16 + r;
                float e = __expf((float)c[fm][fn][r] * INV_C2_X2);
                tsum += (grow == gcol) ? 0.0f : e;
              }
            }
          wsum += tsum;
        }
      }
      if (sn < nsteps) {
        asm volatile("s_waitcnt vmcnt(2)" ::: "memory");
      } else {
        asm volatile("s_waitcnt vmcnt(0)" ::: "memory");
      }
      __builtin_amdgcn_sched_barrier(0);
      __builtin_amdgcn_s_barrier();
    }
  }

  // per-block reduction, fence-free publish + monotonic election
#pragma unroll
  for (int off = 32; off > 0; off >>= 1) wsum += __shfl_down(wsum, off);
  if (lane == 0) red[w] = wsum;
  __syncthreads();
  if (tid == 0) {
    float bsum = 0.0f;
#pragma unroll
    for (int k = 0; k < 8; ++k) bsum += red[k];
    // agent-scope relaxed store -> visible at the device coherent point...
    __hip_atomic_store(&neg_blk[bid], bsum, __ATOMIC_RELAXED,
                       __HIP_MEMORY_SCOPE_AGENT);
    // ...and COMPLETE before the ticket increments (no wbl2/inv needed)
    asm volatile("s_waitcnt vmcnt(0)" ::: "memory");
    int t2 = __hip_atomic_fetch_add(&g_fin, 1, __ATOMIC_RELAXED,
                                    __HIP_MEMORY_SCOPE_AGENT);
    lastblk = ((t2 % NGRAM) == NGRAM - 1) ? 1 : 0;
  }
  __syncthreads();

  if (lastblk) {
    // pos_blk: previous dispatch -> plain loads coherent. neg_blk: written
    // this-dispatch on other XCDs -> agent-scope loads (R4/R6-verified).
    float p = 0.0f, n = 0.0f;
    for (int idx = tid; idx < NPOSB; idx += 512) p += pos_blk[idx];
    for (int idx = tid; idx < NGRAM; idx += 512)
      n += __hip_atomic_load(&neg_blk[idx], __ATOMIC_RELAXED,
                             __HIP_MEMORY_SCOPE_AGENT);
#pragma unroll
    for (int off = 32; off > 0; off >>= 1) {
      p += __shfl_down(p, off);
      n += __shfl_down(n, off);
    }
    if (lane == 0) { pr[w] = p; nr[w] = n; }
    __syncthreads();
    if (tid == 0) {
      float P = 0.0f, N = 0.0f;
#pragma unroll
      for (int k = 0; k < 8; ++k) { P += pr[k]; N += nr[k]; }
      // sum(pos) = (6*B + 2P)/36 = B/6 + P/18 ; sum(neg) = N/(B-1)
      out[0] = (1.0f / 32.0f) * ((float)B_N / 6.0f + P / 18.0f) +
               0.0039f * (N / (float)(B_N - 1));
    }
  }
}

extern "C" void kernel_launch(void* const* d_in, const int* in_sizes, int n_in,
                              void* d_out, int out_size, void* d_ws, size_t ws_size,
                              hipStream_t stream) {
  const float* z = (const float*)d_in[0];
  float* out = (float*)d_out;
  // ws: [0, 4KB) pos partials (1024 f32) | 8KB: neg partials (480 f32) |
  //     32KB: i8 Zn [V][B][D] (6.3 MB). All fully overwritten every launch.
  //     Election counter is a __device__ global (monotonic, no init).
  float* pos_blk = (float*)d_ws;
  float* neg_blk = (float*)((char*)d_ws + 8192);
  signed char* znb = (signed char*)((char*)d_ws + 32768);

  norm_pos_kernel<<<NPOSB, 256, 0, stream>>>(z, znb, pos_blk);
  dim3 grid(NCHUNK, V_N, 1);
  gram_kernel<<<grid, 512, 0, stream>>>(znb, pos_blk, neg_blk, out);
}